// Round 13
// baseline (93.165 us; speedup 1.0000x reference)
//
#include <hip/hip_runtime.h>
#include <math.h>

#define BLOCK 256
#define DPB   128            // directions per block (2 threads per dir)
#define LBv 1e-20f
#define UBv 1e20f

typedef float v2f __attribute__((ext_vector_type(2)));

#if __has_builtin(__builtin_amdgcn_logf) && __has_builtin(__builtin_amdgcn_exp2f)
__device__ __forceinline__ float fast_log2(float x) { return __builtin_amdgcn_logf(x); }
__device__ __forceinline__ float fast_exp2(float x) { return __builtin_amdgcn_exp2f(x); }
#else
__device__ __forceinline__ float fast_log2(float x) { return log2f(x); }
__device__ __forceinline__ float fast_exp2(float x) { return exp2f(x); }
#endif

// One block: 128 directions x 2 V-halves; hot loop processes v-pairs with
// packed f32 (VOP3P v_pk_*) to halve non-trans VALU issue.
__global__ __launch_bounds__(BLOCK) void mcnet_pk(
    const float* __restrict__ verts,   // (NT, V, 3)
    const float* __restrict__ smooth,  // (NT,)
    const float* __restrict__ dirs,    // (D, 3)
    float* __restrict__ out,
    int NT, int V, int D, int SPLIT,   // SPLIT = ceil(D/DPB)
    size_t offDH, size_t offMV, size_t offDIR, size_t offLV, size_t offZ)
{
    __shared__ float red[3 * BLOCK];

    const int tid  = threadIdx.x;
    const int tile = blockIdx.x / SPLIT;
    const int s    = blockIdx.x % SPLIT;

    const float* vp0 = verts + (size_t)tile * V * 3;

    // ---- mean via LDS tree reduction ----
    float sx = 0.f, sy = 0.f, sz = 0.f;
    for (int v = tid; v < V; v += BLOCK) {
        sx += vp0[3 * v + 0]; sy += vp0[3 * v + 1]; sz += vp0[3 * v + 2];
    }
    red[tid] = sx; red[tid + BLOCK] = sy; red[tid + 2 * BLOCK] = sz;
    __syncthreads();
    for (int st = BLOCK / 2; st > 0; st >>= 1) {
        if (tid < st) {
            red[tid]             += red[tid + st];
            red[tid + BLOCK]     += red[tid + BLOCK + st];
            red[tid + 2 * BLOCK] += red[tid + 2 * BLOCK + st];
        }
        __syncthreads();
    }
    const float inv = 1.0f / (float)V;
    const float mx = red[0] * inv, my = red[BLOCK] * inv, mz = red[2 * BLOCK] * inv;

    // ---- small outputs ----
    if (s == 0) {
        for (int v = tid; v < V; v += BLOCK) {
            size_t o = offLV + ((size_t)tile * V + v) * 3;
            out[o + 0] = vp0[3 * v + 0] - mx;
            out[o + 1] = vp0[3 * v + 1] - my;
            out[o + 2] = vp0[3 * v + 2] - mz;
        }
        if (tid == 0) {
            size_t mo = offMV + (size_t)tile * 3;
            out[mo + 0] = mx; out[mo + 1] = my; out[mo + 2] = mz;
        }
    }
    if (blockIdx.x == 0) {
        for (int i = tid; i < D * 3; i += BLOCK)
            out[offDIR + i] = dirs[i];
        if (tid < 2) out[offZ + tid] = 0.f;
    }

    // ---- accumulate over this thread's V-half, two v's per iteration ----
    const int slot = tid & (DPB - 1);
    const int half = tid >> 7;
    const int d    = s * DPB + slot;
    const bool active = (d < D);
    const int dc   = active ? d : (D - 1);

    const float dx = dirs[dc * 3 + 0];
    const float dy = dirs[dc * 3 + 1];
    const float dz = dirs[dc * 3 + 2];
    const float pv = smooth[tile];
    const float c1 = pv - 1.f;
    const float nmd = -(mx * dx + my * dy + mz * dz);

    const int vh = V >> 1;
    const int v0 = half ? vh : 0;
    const int v1 = half ? V : vh;

    const v2f zero2 = {0.f, 0.f};
    v2f S2 = zero2, Wx2 = zero2, Wy2 = zero2, Wz2 = zero2, Ws2 = zero2;
    const v2f dx2 = {dx, dx}, dy2 = {dy, dy}, dz2 = {dz, dz};
    const v2f nmd2 = {nmd, nmd}, c12 = {c1, c1};

    #pragma unroll 4
    for (int v = v0; v < v1; v += 2) {
        const float* p = vp0 + 3 * v;
        v2f vx = {p[0], p[3]};
        v2f vy = {p[1], p[4]};
        v2f vz = {p[2], p[5]};
        v2f z  = __builtin_elementwise_fma(vx, dx2,
                 __builtin_elementwise_fma(vy, dy2,
                 __builtin_elementwise_fma(vz, dz2, nmd2)));
        v2f zc = __builtin_elementwise_max(z, zero2);
        v2f cl = c12 * (v2f){fast_log2(zc.x), fast_log2(zc.y)};  // -inf at 0
        v2f w  = {fast_exp2(cl.x), fast_exp2(cl.y)};             // z^(p-1), 0 at z<=0
        S2  = __builtin_elementwise_fma(w, zc, S2);              // z^p
        Wx2 = __builtin_elementwise_fma(w, vx, Wx2);
        Wy2 = __builtin_elementwise_fma(w, vy, Wy2);
        Wz2 = __builtin_elementwise_fma(w, vz, Wz2);
        Ws2 += w;
    }

    float S  = S2.x + S2.y;
    float Wx = Wx2.x + Wx2.y;
    float Wy = Wy2.x + Wy2.y;
    float Wz = Wz2.x + Wz2.y;
    float Ws = Ws2.x + Ws2.y;

    // ---- combine halves via LDS ----
    __syncthreads();
    if (half) {
        red[slot + 0 * DPB] = S;
        red[slot + 1 * DPB] = Wx;
        red[slot + 2 * DPB] = Wy;
        red[slot + 3 * DPB] = Wz;
        red[slot + 4 * DPB] = Ws;
    }
    __syncthreads();
    if (half || !active) return;

    S  += red[slot + 0 * DPB];
    Wx += red[slot + 1 * DPB];
    Wy += red[slot + 2 * DPB];
    Wz += red[slot + 3 * DPB];
    Ws += red[slot + 4 * DPB];

    const float Sthresh = (float)V * 1e-10f;
    size_t po  = ((size_t)tile * D + d) * 3;
    size_t dho = offDH + ((size_t)tile * D + d) * 4;

    if (S >= Sthresh) {
        // S >= V*1e-10 => zmax^p >= 1e-10: no k-rescale, exponents bounded,
        // LB floors negligible, UB clip unreachable.
        float h = fminf(fmaxf(fast_exp2(fast_log2(S) * (1.f / pv)), LBv), UBv);
        float scale = fast_exp2(-c1 * fast_log2(h));   // h^-(p-1)
        float ax = fmaf(-mx, Ws, Wx);                  // sum w*lv
        float ay = fmaf(-my, Ws, Wy);
        float az = fmaf(-mz, Ws, Wz);
        out[po + 0] = fmaf(ax, scale, mx);
        out[po + 1] = fmaf(ay, scale, my);
        out[po + 2] = fmaf(az, scale, mz);
        out[dho + 0] = dx;
        out[dho + 1] = dy;
        out[dho + 2] = dz;
        out[dho + 3] = h;                               // k == 1
    } else {
        // ---- literal reference semantics (cold; never taken for bench data) ----
        float zmax = 0.f;
        for (int v = 0; v < V; ++v) {
            float z = fmaf(vp0[3 * v] - mx, dx,
                      fmaf(vp0[3 * v + 1] - my, dy, (vp0[3 * v + 2] - mz) * dz));
            zmax = fmaxf(zmax, z);
        }
        float zm_log   = (zmax > 0.f) ? log10f(zmax) : -INFINITY;
        float exponent = zm_log * pv;
        float lk = (exponent < -20.f) ? (-20.f - exponent) / pv : 0.f;
        float kk = powf(10.f, fminf(fmaxf(ceilf(lk), 0.f), UBv));

        float sum = 0.f;
        for (int v = 0; v < V; ++v) {
            float z = fmaf(vp0[3 * v] - mx, dx,
                      fmaf(vp0[3 * v + 1] - my, dy, (vp0[3 * v + 2] - mz) * dz));
            float zms = fmaxf(z, 0.f) * kk;
            float w   = (zms > 0.f) ? fminf(fmaxf(powf(zms, pv), LBv), UBv) : 0.f;
            sum += w;
        }
        float h = fminf(fmaxf(powf(sum, 1.f / pv), LBv), UBv);

        float bx = 0.f, by = 0.f, bz = 0.f;
        for (int v = 0; v < V; ++v) {
            float lx = vp0[3 * v] - mx, ly = vp0[3 * v + 1] - my, lz = vp0[3 * v + 2] - mz;
            float z     = fmaf(lx, dx, fmaf(ly, dy, lz * dz));
            float zms   = fmaxf(z, 0.f) * kk;
            float ratio = zms / h;
            float w = (ratio > 0.f) ? fminf(fmaxf(powf(ratio, c1), LBv), UBv) : LBv;
            bx = fmaf(w, lx, bx);
            by = fmaf(w, ly, by);
            bz = fmaf(w, lz, bz);
        }
        out[po + 0] = bx + mx;
        out[po + 1] = by + my;
        out[po + 2] = bz + mz;
        out[dho + 0] = dx;
        out[dho + 1] = dy;
        out[dho + 2] = dz;
        out[dho + 3] = h / kk;
    }
}

extern "C" void kernel_launch(void* const* d_in, const int* in_sizes, int n_in,
                              void* d_out, int out_size, void* d_ws, size_t ws_size,
                              hipStream_t stream) {
    const float* verts  = (const float*)d_in[0];
    const float* smooth = (const float*)d_in[1];
    const float* dirs   = (const float*)d_in[2];
    float* out = (float*)d_out;

    const int NT = in_sizes[1];
    const int D  = in_sizes[2] / 3;
    const int V  = in_sizes[0] / (3 * NT);
    const int SPLIT = (D + DPB - 1) / DPB;

    const size_t NTD = (size_t)NT * D;
    const size_t offDH  = NTD * 3;                       // after points
    const size_t offMV  = offDH  + NTD * 4;              // after direction_h
    const size_t offDIR = offMV  + (size_t)NT * 3;       // after mean_v
    const size_t offLV  = offDIR + (size_t)D * 3;        // after directions
    const size_t offZ   = offLV  + (size_t)NT * V * 3;   // after local_vertices

    dim3 grid(NT * SPLIT);
    dim3 block(BLOCK);
    hipLaunchKernelGGL(mcnet_pk, grid, block, 0, stream,
                       verts, smooth, dirs, out,
                       NT, V, D, SPLIT, offDH, offMV, offDIR, offLV, offZ);
}